// Round 1
// baseline (12678.623 us; speedup 1.0000x reference)
//
#include <hip/hip_runtime.h>
#include <hip/hip_bf16.h>
#include <stdint.h>

#define N_NODES 100000
#define N_EDGES 1600000
#define N_GRAPHS 512
#define IN_F 50
#define HID 128

__device__ __forceinline__ float bf2f(unsigned short s) {
    return __uint_as_float(((unsigned)s) << 16);
}
__device__ __forceinline__ unsigned short f2bf(float f) {
    unsigned u = __float_as_uint(f);
    u = (u + 0x7FFFu + ((u >> 16) & 1u)) >> 16;   // round-to-nearest-even
    return (unsigned short)u;
}

// W[128][K] -> Wt[K][128]
__global__ void transpose_w(const float* __restrict__ W, float* __restrict__ Wt, int K) {
    int idx = blockIdx.x * 256 + threadIdx.x;
    if (idx < K * 128) {
        int k = idx >> 7, n = idx & 127;
        Wt[k * 128 + n] = W[n * K + k];
    }
}

// counts[g] = #nodes in graph g (batch is sorted) -- atomic-free binary search
__global__ void count_nodes(const int* __restrict__ batch, float* __restrict__ counts) {
    int g = blockIdx.x * blockDim.x + threadIdx.x;
    if (g >= N_GRAPHS) return;
    int lo = 0, hi = N_NODES;
    while (lo < hi) { int m = (lo + hi) >> 1; if (batch[m] < g) lo = m + 1; else hi = m; }
    int lo2 = lo, hi2 = N_NODES;
    while (lo2 < hi2) { int m = (lo2 + hi2) >> 1; if (batch[m] < g + 1) lo2 = m + 1; else hi2 = m; }
    counts[g] = (float)(lo2 - lo);
}

// layer-1 aggregation in input space (F=50, f32): one wave per edge
__global__ void scatter_f50(const float* __restrict__ x, const int* __restrict__ src,
                            const int* __restrict__ dst, float* __restrict__ agg) {
    int gid = blockIdx.x * blockDim.x + threadIdx.x;
    int lane = threadIdx.x & 63;
    int wid = gid >> 6;
    int nw = (gridDim.x * blockDim.x) >> 6;
    for (int e = wid; e < N_EDGES; e += nw) {
        int s = src[e], d = dst[e];
        if (lane < IN_F) atomicAdd(&agg[d * IN_F + lane], x[s * IN_F + lane]);
    }
}

// layers 2/3 aggregation (F=128, bf16 source): thread per (edge, 8-feature chunk)
__global__ void scatter_bf128(const unsigned short* __restrict__ h, const int* __restrict__ src,
                              const int* __restrict__ dst, float* __restrict__ agg) {
    int gid = blockIdx.x * blockDim.x + threadIdx.x;
    const int total = N_EDGES * 16;
    int stride = gridDim.x * blockDim.x;
    for (int i = gid; i < total; i += stride) {
        int e = i >> 4, c = i & 15;
        int s = src[e], d = dst[e];
        uint4 v = *reinterpret_cast<const uint4*>(h + (size_t)s * HID + c * 8);
        const unsigned short* u = reinterpret_cast<const unsigned short*>(&v);
        float* ap = agg + (size_t)d * HID + c * 8;
#pragma unroll
        for (int j = 0; j < 8; j++) atomicAdd(ap + j, bf2f(u[j]));
    }
}

// h_out = [relu](agg @ W_rel^T + b + X @ W_root^T); optional fused mean-pool scatter.
// Block = 256 threads = 8 rows x 32 col-groups (4 cols each). A-rows staged in LDS,
// Wt (pre-transposed [K][128]) read as coalesced float4 (L1/L2 resident, reused by all blocks).
template <int K, int KP, bool XBF16, bool RELU, bool POOL>
__global__ __launch_bounds__(256) void fused_linear(
    const float* __restrict__ A, const void* __restrict__ Xv,
    const float* __restrict__ Wt_rel, const float* __restrict__ Wt_root,
    const float* __restrict__ bias, unsigned short* __restrict__ hout,
    const int* __restrict__ batch, float* __restrict__ pooled) {
    __shared__ float As[8][KP];
    __shared__ float Xs[8][KP];
    const int base = blockIdx.x * 8;
    const int tid = threadIdx.x;
    for (int idx = tid; idx < 8 * KP; idx += 256) {
        int r = idx / KP, k = idx - r * KP;
        int row = base + r;
        float av = 0.f, xv = 0.f;
        if (k < K) {
            av = A[(size_t)row * K + k];
            if (XBF16) xv = bf2f(reinterpret_cast<const unsigned short*>(Xv)[(size_t)row * K + k]);
            else       xv = reinterpret_cast<const float*>(Xv)[(size_t)row * K + k];
        }
        As[r][k] = av; Xs[r][k] = xv;
    }
    __syncthreads();
    const int r = tid >> 5;
    const int n0 = (tid & 31) * 4;
    float4 acc;
    acc.x = bias[n0]; acc.y = bias[n0 + 1]; acc.z = bias[n0 + 2]; acc.w = bias[n0 + 3];
#pragma unroll
    for (int k4 = 0; k4 < KP / 4; ++k4) {
        float4 a4 = *reinterpret_cast<const float4*>(&As[r][k4 * 4]);
        float4 x4 = *reinterpret_cast<const float4*>(&Xs[r][k4 * 4]);
        float av[4] = {a4.x, a4.y, a4.z, a4.w};
        float xv[4] = {x4.x, x4.y, x4.z, x4.w};
        const float* wr = &Wt_rel[(k4 * 4) * 128 + n0];
        const float* wo = &Wt_root[(k4 * 4) * 128 + n0];
#pragma unroll
        for (int j = 0; j < 4; j++) {
            float4 w1 = *reinterpret_cast<const float4*>(wr + j * 128);
            float4 w2 = *reinterpret_cast<const float4*>(wo + j * 128);
            acc.x += av[j] * w1.x + xv[j] * w2.x;
            acc.y += av[j] * w1.y + xv[j] * w2.y;
            acc.z += av[j] * w1.z + xv[j] * w2.z;
            acc.w += av[j] * w1.w + xv[j] * w2.w;
        }
    }
    const int row = base + r;
    if (RELU) {
        unsigned a0 = f2bf(fmaxf(acc.x, 0.f)), a1 = f2bf(fmaxf(acc.y, 0.f));
        unsigned a2 = f2bf(fmaxf(acc.z, 0.f)), a3 = f2bf(fmaxf(acc.w, 0.f));
        uint2 pk; pk.x = a0 | (a1 << 16); pk.y = a2 | (a3 << 16);
        *reinterpret_cast<uint2*>(hout + (size_t)row * HID + n0) = pk;
    }
    if (POOL) {
        int g = batch[row];
        float* pp = pooled + (size_t)g * HID + n0;
        atomicAdd(pp + 0, acc.x); atomicAdd(pp + 1, acc.y);
        atomicAdd(pp + 2, acc.z); atomicAdd(pp + 3, acc.w);
    }
}

__global__ void final_linear(const float* __restrict__ pooled, const float* __restrict__ counts,
                             const float* __restrict__ W_lin, const float* __restrict__ b_lin,
                             float* __restrict__ out) {
    __shared__ float p[HID];
    int g = blockIdx.x, tid = threadIdx.x;
    float c = fmaxf(counts[g], 1.f);
    p[tid] = pooled[(size_t)g * HID + tid] / c;
    __syncthreads();
    if (tid < 4) {
        float s = b_lin[tid];
#pragma unroll 8
        for (int k = 0; k < HID; k++) s += p[k] * W_lin[tid * HID + k];
        out[g * 4 + tid] = s;
    }
}

extern "C" void kernel_launch(void* const* d_in, const int* in_sizes, int n_in,
                              void* d_out, int out_size, void* d_ws, size_t ws_size,
                              hipStream_t stream) {
    (void)in_sizes; (void)n_in; (void)out_size; (void)ws_size;
    const float* x      = (const float*)d_in[0];
    const int*   ei     = (const int*)d_in[1];
    const int*   batch  = (const int*)d_in[2];
    const float* W_rel1 = (const float*)d_in[3];
    const float* b_rel1 = (const float*)d_in[4];
    const float* W_root1= (const float*)d_in[5];
    const float* W_rel2 = (const float*)d_in[6];
    const float* b_rel2 = (const float*)d_in[7];
    const float* W_root2= (const float*)d_in[8];
    const float* W_rel3 = (const float*)d_in[9];
    const float* b_rel3 = (const float*)d_in[10];
    const float* W_root3= (const float*)d_in[11];
    const float* W_lin  = (const float*)d_in[12];
    const float* b_lin  = (const float*)d_in[13];
    const int* src = ei;
    const int* dst = ei + N_EDGES;

    char* ws = (char*)d_ws;
    size_t off = 0;
    auto alloc = [&](size_t bytes) { void* p = ws + off; off += (bytes + 255) & ~(size_t)255; return p; };
    float*          agg      = (float*)alloc((size_t)N_NODES * HID * 4);       // 51.2 MB (reused all layers)
    unsigned short* h1       = (unsigned short*)alloc((size_t)N_NODES * HID * 2); // 25.6 MB
    unsigned short* h2       = (unsigned short*)alloc((size_t)N_NODES * HID * 2); // 25.6 MB
    float*          Wt_rel1  = (float*)alloc(52 * 128 * 4);
    float*          Wt_root1 = (float*)alloc(52 * 128 * 4);
    float*          Wt_rel2  = (float*)alloc(128 * 128 * 4);
    float*          Wt_root2 = (float*)alloc(128 * 128 * 4);
    float*          Wt_rel3  = (float*)alloc(128 * 128 * 4);
    float*          Wt_root3 = (float*)alloc(128 * 128 * 4);
    float*          pooled   = (float*)alloc((size_t)N_GRAPHS * HID * 4);
    float*          counts   = (float*)alloc(N_GRAPHS * 4);

    // weight transposes (K=50 padded to 52 with zeros for uniform float4 k-loop)
    hipMemsetAsync(Wt_rel1, 0, 52 * 128 * 4, stream);
    hipMemsetAsync(Wt_root1, 0, 52 * 128 * 4, stream);
    transpose_w<<<(50 * 128 + 255) / 256, 256, 0, stream>>>(W_rel1, Wt_rel1, 50);
    transpose_w<<<(50 * 128 + 255) / 256, 256, 0, stream>>>(W_root1, Wt_root1, 50);
    transpose_w<<<64, 256, 0, stream>>>(W_rel2, Wt_rel2, 128);
    transpose_w<<<64, 256, 0, stream>>>(W_root2, Wt_root2, 128);
    transpose_w<<<64, 256, 0, stream>>>(W_rel3, Wt_rel3, 128);
    transpose_w<<<64, 256, 0, stream>>>(W_root3, Wt_root3, 128);
    hipMemsetAsync(pooled, 0, (size_t)N_GRAPHS * HID * 4, stream);
    count_nodes<<<2, 256, 0, stream>>>(batch, counts);

    // ---- layer 1 (aggregate x at F=50, then fused linears + relu -> h1 bf16)
    hipMemsetAsync(agg, 0, (size_t)N_NODES * IN_F * 4, stream);
    scatter_f50<<<2048, 256, 0, stream>>>(x, src, dst, agg);
    fused_linear<50, 52, false, true, false><<<N_NODES / 8, 256, 0, stream>>>(
        agg, x, Wt_rel1, Wt_root1, b_rel1, h1, nullptr, nullptr);

    // ---- layer 2
    hipMemsetAsync(agg, 0, (size_t)N_NODES * HID * 4, stream);
    scatter_bf128<<<4096, 256, 0, stream>>>(h1, src, dst, agg);
    fused_linear<128, 128, true, true, false><<<N_NODES / 8, 256, 0, stream>>>(
        agg, h1, Wt_rel2, Wt_root2, b_rel2, h2, nullptr, nullptr);

    // ---- layer 3 (no relu; fused mean-pool scatter into pooled)
    hipMemsetAsync(agg, 0, (size_t)N_NODES * HID * 4, stream);
    scatter_bf128<<<4096, 256, 0, stream>>>(h2, src, dst, agg);
    fused_linear<128, 128, true, false, true><<<N_NODES / 8, 256, 0, stream>>>(
        agg, h2, Wt_rel3, Wt_root3, b_rel3, nullptr, batch, pooled);

    final_linear<<<N_GRAPHS, HID, 0, stream>>>(pooled, counts, W_lin, b_lin, (float*)d_out);
}

// Round 2
// 1800.116 us; speedup vs baseline: 7.0432x; 7.0432x over previous
//
#include <hip/hip_runtime.h>
#include <hip/hip_bf16.h>
#include <stdint.h>

#define N_NODES 100000
#define N_EDGES 1600000
#define N_GRAPHS 512
#define IN_F 50
#define HID 128

__device__ __forceinline__ float bf2f(unsigned short s) {
    return __uint_as_float(((unsigned)s) << 16);
}
__device__ __forceinline__ unsigned short f2bf(float f) {
    unsigned u = __float_as_uint(f);
    u = (u + 0x7FFFu + ((u >> 16) & 1u)) >> 16;   // round-to-nearest-even
    return (unsigned short)u;
}

// W[128][K] -> Wt[K][128]
__global__ void transpose_w(const float* __restrict__ W, float* __restrict__ Wt, int K) {
    int idx = blockIdx.x * 256 + threadIdx.x;
    if (idx < K * 128) {
        int k = idx >> 7, n = idx & 127;
        Wt[k * 128 + n] = W[n * K + k];
    }
}

// counts[g] = #nodes in graph g (batch is sorted) -- atomic-free binary search
__global__ void count_nodes(const int* __restrict__ batch, float* __restrict__ counts) {
    int g = blockIdx.x * blockDim.x + threadIdx.x;
    if (g >= N_GRAPHS) return;
    int lo = 0, hi = N_NODES;
    while (lo < hi) { int m = (lo + hi) >> 1; if (batch[m] < g) lo = m + 1; else hi = m; }
    int lo2 = lo, hi2 = N_NODES;
    while (lo2 < hi2) { int m = (lo2 + hi2) >> 1; if (batch[m] < g + 1) lo2 = m + 1; else hi2 = m; }
    counts[g] = (float)(lo2 - lo);
}

// ---------------- CSR build ----------------
__global__ void deg_hist(const int* __restrict__ dst, int* __restrict__ deg) {
    int gid = blockIdx.x * blockDim.x + threadIdx.x;
    int stride = gridDim.x * blockDim.x;
    for (int e = gid; e < N_EDGES; e += stride) atomicAdd(&deg[dst[e]], 1);
}

// single-block exclusive scan of 100k degrees -> rowptr[100001], cursor copy
#define SCAN_T 1024
#define SCAN_CHUNK 98   // 1024*98 = 100352 >= 100000
__global__ __launch_bounds__(SCAN_T) void scan_deg(const int* __restrict__ deg,
                                                   int* __restrict__ rowptr,
                                                   int* __restrict__ cursor) {
    __shared__ int part[SCAN_T];
    int t = threadIdx.x;
    int begin = t * SCAN_CHUNK;
    int end = begin + SCAN_CHUNK; if (end > N_NODES) end = N_NODES;
    if (begin > N_NODES) begin = N_NODES;
    int s = 0;
    for (int i = begin; i < end; i++) s += deg[i];
    part[t] = s;
    __syncthreads();
    for (int off = 1; off < SCAN_T; off <<= 1) {
        int u = (t >= off) ? part[t - off] : 0;
        __syncthreads();
        part[t] += u;
        __syncthreads();
    }
    int run = part[t] - s;   // exclusive prefix of this thread's chunk
    for (int i = begin; i < end; i++) {
        rowptr[i] = run; cursor[i] = run;
        run += deg[i];
    }
    if (t == SCAN_T - 1) rowptr[N_NODES] = part[SCAN_T - 1];
}

__global__ void csr_fill(const int* __restrict__ src, const int* __restrict__ dst,
                         int* __restrict__ cursor, int* __restrict__ csr_src) {
    int gid = blockIdx.x * blockDim.x + threadIdx.x;
    int stride = gridDim.x * blockDim.x;
    for (int e = gid; e < N_EDGES; e += stride) {
        int d = dst[e];
        int p = atomicAdd(&cursor[d], 1);
        csr_src[p] = src[e];
    }
}

// ---------------- pull aggregation ----------------
// wave per node, F=50 f32: lanes 0..49 hold one feature each
__global__ __launch_bounds__(256) void gather_f50(const float* __restrict__ x,
                                                  const int* __restrict__ rowptr,
                                                  const int* __restrict__ csr_src,
                                                  float* __restrict__ agg) {
    int gid = blockIdx.x * blockDim.x + threadIdx.x;
    int n = gid >> 6;
    int lane = threadIdx.x & 63;
    if (n >= N_NODES) return;
    int jb = rowptr[n], je = rowptr[n + 1];
    float acc = 0.f;
    int j = jb;
    for (; j + 1 < je; j += 2) {
        int s0 = csr_src[j], s1 = csr_src[j + 1];
        float v0 = 0.f, v1 = 0.f;
        if (lane < IN_F) { v0 = x[(size_t)s0 * IN_F + lane]; v1 = x[(size_t)s1 * IN_F + lane]; }
        acc += v0 + v1;
    }
    if (j < je) {
        int s0 = csr_src[j];
        if (lane < IN_F) acc += x[(size_t)s0 * IN_F + lane];
    }
    if (lane < IN_F) agg[(size_t)n * IN_F + lane] = acc;
}

// wave per node, F=128 bf16 source: lane holds 2 features (one dword)
__global__ __launch_bounds__(256) void gather_bf128(const unsigned short* __restrict__ h,
                                                    const int* __restrict__ rowptr,
                                                    const int* __restrict__ csr_src,
                                                    float* __restrict__ agg) {
    int gid = blockIdx.x * blockDim.x + threadIdx.x;
    int n = gid >> 6;
    int lane = threadIdx.x & 63;
    if (n >= N_NODES) return;
    int jb = rowptr[n], je = rowptr[n + 1];
    float acc0 = 0.f, acc1 = 0.f;
    const unsigned* hu = reinterpret_cast<const unsigned*>(h);
    int j = jb;
    for (; j + 1 < je; j += 2) {
        int s0 = csr_src[j], s1 = csr_src[j + 1];
        unsigned v0 = hu[(size_t)s0 * 64 + lane];
        unsigned v1 = hu[(size_t)s1 * 64 + lane];
        acc0 += bf2f((unsigned short)(v0 & 0xFFFF)) + bf2f((unsigned short)(v1 & 0xFFFF));
        acc1 += bf2f((unsigned short)(v0 >> 16)) + bf2f((unsigned short)(v1 >> 16));
    }
    if (j < je) {
        int s0 = csr_src[j];
        unsigned v0 = hu[(size_t)s0 * 64 + lane];
        acc0 += bf2f((unsigned short)(v0 & 0xFFFF));
        acc1 += bf2f((unsigned short)(v0 >> 16));
    }
    float2 out; out.x = acc0; out.y = acc1;
    *reinterpret_cast<float2*>(agg + (size_t)n * HID + lane * 2) = out;
}

// h_out = [relu](agg @ W_rel^T + b + X @ W_root^T); optional fused mean-pool scatter.
// Block = 256 threads = 8 rows x 32 col-groups (4 cols each). A-rows staged in LDS,
// Wt (pre-transposed [K][128]) read as coalesced float4 (L2 resident, reused by all blocks).
// In-place safe (hout may alias Xv): all reads of the block's rows land in LDS
// before any write.
template <int K, int KP, bool XBF16, bool RELU, bool POOL>
__global__ __launch_bounds__(256) void fused_linear(
    const float* __restrict__ A, const void* __restrict__ Xv,
    const float* __restrict__ Wt_rel, const float* __restrict__ Wt_root,
    const float* __restrict__ bias, unsigned short* __restrict__ hout,
    const int* __restrict__ batch, float* __restrict__ pooled) {
    __shared__ float As[8][KP];
    __shared__ float Xs[8][KP];
    const int base = blockIdx.x * 8;
    const int tid = threadIdx.x;
    for (int idx = tid; idx < 8 * KP; idx += 256) {
        int r = idx / KP, k = idx - r * KP;
        int row = base + r;
        float av = 0.f, xv = 0.f;
        if (k < K) {
            av = A[(size_t)row * K + k];
            if (XBF16) xv = bf2f(reinterpret_cast<const unsigned short*>(Xv)[(size_t)row * K + k]);
            else       xv = reinterpret_cast<const float*>(Xv)[(size_t)row * K + k];
        }
        As[r][k] = av; Xs[r][k] = xv;
    }
    __syncthreads();
    const int r = tid >> 5;
    const int n0 = (tid & 31) * 4;
    float4 acc;
    acc.x = bias[n0]; acc.y = bias[n0 + 1]; acc.z = bias[n0 + 2]; acc.w = bias[n0 + 3];
#pragma unroll
    for (int k4 = 0; k4 < KP / 4; ++k4) {
        float4 a4 = *reinterpret_cast<const float4*>(&As[r][k4 * 4]);
        float4 x4 = *reinterpret_cast<const float4*>(&Xs[r][k4 * 4]);
        float av[4] = {a4.x, a4.y, a4.z, a4.w};
        float xv[4] = {x4.x, x4.y, x4.z, x4.w};
        const float* wr = &Wt_rel[(k4 * 4) * 128 + n0];
        const float* wo = &Wt_root[(k4 * 4) * 128 + n0];
#pragma unroll
        for (int j = 0; j < 4; j++) {
            float4 w1 = *reinterpret_cast<const float4*>(wr + j * 128);
            float4 w2 = *reinterpret_cast<const float4*>(wo + j * 128);
            acc.x += av[j] * w1.x + xv[j] * w2.x;
            acc.y += av[j] * w1.y + xv[j] * w2.y;
            acc.z += av[j] * w1.z + xv[j] * w2.z;
            acc.w += av[j] * w1.w + xv[j] * w2.w;
        }
    }
    const int row = base + r;
    if (RELU) {
        unsigned a0 = f2bf(fmaxf(acc.x, 0.f)), a1 = f2bf(fmaxf(acc.y, 0.f));
        unsigned a2 = f2bf(fmaxf(acc.z, 0.f)), a3 = f2bf(fmaxf(acc.w, 0.f));
        uint2 pk; pk.x = a0 | (a1 << 16); pk.y = a2 | (a3 << 16);
        *reinterpret_cast<uint2*>(hout + (size_t)row * HID + n0) = pk;
    }
    if (POOL) {
        int g = batch[row];
        float* pp = pooled + (size_t)g * HID + n0;
        atomicAdd(pp + 0, acc.x); atomicAdd(pp + 1, acc.y);
        atomicAdd(pp + 2, acc.z); atomicAdd(pp + 3, acc.w);
    }
}

__global__ void final_linear(const float* __restrict__ pooled, const float* __restrict__ counts,
                             const float* __restrict__ W_lin, const float* __restrict__ b_lin,
                             float* __restrict__ out) {
    __shared__ float p[HID];
    int g = blockIdx.x, tid = threadIdx.x;
    float c = fmaxf(counts[g], 1.f);
    p[tid] = pooled[(size_t)g * HID + tid] / c;
    __syncthreads();
    if (tid < 4) {
        float s = b_lin[tid];
#pragma unroll 8
        for (int k = 0; k < HID; k++) s += p[k] * W_lin[tid * HID + k];
        out[g * 4 + tid] = s;
    }
}

extern "C" void kernel_launch(void* const* d_in, const int* in_sizes, int n_in,
                              void* d_out, int out_size, void* d_ws, size_t ws_size,
                              hipStream_t stream) {
    (void)in_sizes; (void)n_in; (void)out_size; (void)ws_size;
    const float* x      = (const float*)d_in[0];
    const int*   ei     = (const int*)d_in[1];
    const int*   batch  = (const int*)d_in[2];
    const float* W_rel1 = (const float*)d_in[3];
    const float* b_rel1 = (const float*)d_in[4];
    const float* W_root1= (const float*)d_in[5];
    const float* W_rel2 = (const float*)d_in[6];
    const float* b_rel2 = (const float*)d_in[7];
    const float* W_root2= (const float*)d_in[8];
    const float* W_rel3 = (const float*)d_in[9];
    const float* b_rel3 = (const float*)d_in[10];
    const float* W_root3= (const float*)d_in[11];
    const float* W_lin  = (const float*)d_in[12];
    const float* b_lin  = (const float*)d_in[13];
    const int* src = ei;
    const int* dst = ei + N_EDGES;

    char* ws = (char*)d_ws;
    size_t off = 0;
    auto alloc = [&](size_t bytes) { void* p = ws + off; off += (bytes + 255) & ~(size_t)255; return p; };
    float*          agg      = (float*)alloc((size_t)N_NODES * HID * 4);          // 51.2 MB (all layers)
    unsigned short* h1       = (unsigned short*)alloc((size_t)N_NODES * HID * 2); // 25.6 MB (layers 2,3 in-place)
    int*            deg      = (int*)alloc((size_t)N_NODES * 4);
    int*            rowptr   = (int*)alloc((size_t)(N_NODES + 1) * 4);
    int*            cursor   = (int*)alloc((size_t)N_NODES * 4);
    int*            csr_src  = (int*)alloc((size_t)N_EDGES * 4);                  // 6.4 MB
    float*          Wt_rel1  = (float*)alloc(52 * 128 * 4);
    float*          Wt_root1 = (float*)alloc(52 * 128 * 4);
    float*          Wt_rel2  = (float*)alloc(128 * 128 * 4);
    float*          Wt_root2 = (float*)alloc(128 * 128 * 4);
    float*          Wt_rel3  = (float*)alloc(128 * 128 * 4);
    float*          Wt_root3 = (float*)alloc(128 * 128 * 4);
    float*          pooled   = (float*)alloc((size_t)N_GRAPHS * HID * 4);
    float*          counts   = (float*)alloc(N_GRAPHS * 4);

    // ---- CSR build (no feature atomics anywhere after this)
    hipMemsetAsync(deg, 0, (size_t)N_NODES * 4, stream);
    deg_hist<<<2048, 256, 0, stream>>>(dst, deg);
    scan_deg<<<1, SCAN_T, 0, stream>>>(deg, rowptr, cursor);
    csr_fill<<<2048, 256, 0, stream>>>(src, dst, cursor, csr_src);

    // ---- weight transposes (K=50 padded to 52 with zeros for uniform float4 k-loop)
    hipMemsetAsync(Wt_rel1, 0, 52 * 128 * 4, stream);
    hipMemsetAsync(Wt_root1, 0, 52 * 128 * 4, stream);
    transpose_w<<<(50 * 128 + 255) / 256, 256, 0, stream>>>(W_rel1, Wt_rel1, 50);
    transpose_w<<<(50 * 128 + 255) / 256, 256, 0, stream>>>(W_root1, Wt_root1, 50);
    transpose_w<<<64, 256, 0, stream>>>(W_rel2, Wt_rel2, 128);
    transpose_w<<<64, 256, 0, stream>>>(W_root2, Wt_root2, 128);
    transpose_w<<<64, 256, 0, stream>>>(W_rel3, Wt_rel3, 128);
    transpose_w<<<64, 256, 0, stream>>>(W_root3, Wt_root3, 128);
    hipMemsetAsync(pooled, 0, (size_t)N_GRAPHS * HID * 4, stream);
    count_nodes<<<2, 256, 0, stream>>>(batch, counts);

    const int GATHER_BLOCKS = (N_NODES * 64 + 255) / 256;  // wave per node

    // ---- layer 1: pull-aggregate x (F=50), fused linears + relu -> h1 (bf16)
    gather_f50<<<GATHER_BLOCKS, 256, 0, stream>>>(x, rowptr, csr_src, agg);
    fused_linear<50, 52, false, true, false><<<N_NODES / 8, 256, 0, stream>>>(
        agg, x, Wt_rel1, Wt_root1, b_rel1, h1, nullptr, nullptr);

    // ---- layer 2: pull-aggregate h1 (F=128 bf16), linears + relu -> h1 (in-place)
    gather_bf128<<<GATHER_BLOCKS, 256, 0, stream>>>(h1, rowptr, csr_src, agg);
    fused_linear<128, 128, true, true, false><<<N_NODES / 8, 256, 0, stream>>>(
        agg, h1, Wt_rel2, Wt_root2, b_rel2, h1, nullptr, nullptr);

    // ---- layer 3: pull-aggregate h1, linears (no relu) + fused mean-pool scatter
    gather_bf128<<<GATHER_BLOCKS, 256, 0, stream>>>(h1, rowptr, csr_src, agg);
    fused_linear<128, 128, true, false, true><<<N_NODES / 8, 256, 0, stream>>>(
        agg, h1, Wt_rel3, Wt_root3, b_rel3, nullptr, batch, pooled);

    final_linear<<<N_GRAPHS, HID, 0, stream>>>(pooled, counts, W_lin, b_lin, (float*)d_out);
}

// Round 3
// 1139.504 us; speedup vs baseline: 11.1264x; 1.5797x over previous
//
#include <hip/hip_runtime.h>
#include <hip/hip_bf16.h>
#include <stdint.h>

#define N_NODES 100000
#define N_EDGES 1600000
#define N_GRAPHS 512
#define IN_F 50
#define HID 128

typedef __attribute__((ext_vector_type(8))) short bf16x8;
typedef __attribute__((ext_vector_type(4))) float f32x4;

__device__ __forceinline__ float bf2f(unsigned short s) {
    return __uint_as_float(((unsigned)s) << 16);
}
__device__ __forceinline__ unsigned short f2bf(float f) {
    unsigned u = __float_as_uint(f);
    u = (u + 0x7FFFu + ((u >> 16) & 1u)) >> 16;   // round-to-nearest-even
    return (unsigned short)u;
}

// counts[g] = #nodes in graph g (batch is sorted) -- atomic-free binary search
__global__ void count_nodes(const int* __restrict__ batch, float* __restrict__ counts) {
    int g = blockIdx.x * blockDim.x + threadIdx.x;
    if (g >= N_GRAPHS) return;
    int lo = 0, hi = N_NODES;
    while (lo < hi) { int m = (lo + hi) >> 1; if (batch[m] < g) lo = m + 1; else hi = m; }
    int lo2 = lo, hi2 = N_NODES;
    while (lo2 < hi2) { int m = (lo2 + hi2) >> 1; if (batch[m] < g + 1) lo2 = m + 1; else hi2 = m; }
    counts[g] = (float)(lo2 - lo);
}

// ---------------- CSR build ----------------
__global__ void deg_hist(const int* __restrict__ dst, int* __restrict__ deg) {
    int gid = blockIdx.x * blockDim.x + threadIdx.x;
    int stride = gridDim.x * blockDim.x;
    for (int e = gid; e < N_EDGES; e += stride) atomicAdd(&deg[dst[e]], 1);
}

#define SCAN_T 1024
#define SCAN_CHUNK 98   // 1024*98 = 100352 >= 100000
__global__ __launch_bounds__(SCAN_T) void scan_deg(const int* __restrict__ deg,
                                                   int* __restrict__ rowptr,
                                                   int* __restrict__ cursor) {
    __shared__ int part[SCAN_T];
    int t = threadIdx.x;
    int begin = t * SCAN_CHUNK;
    int end = begin + SCAN_CHUNK; if (end > N_NODES) end = N_NODES;
    if (begin > N_NODES) begin = N_NODES;
    int s = 0;
    for (int i = begin; i < end; i++) s += deg[i];
    part[t] = s;
    __syncthreads();
    for (int off = 1; off < SCAN_T; off <<= 1) {
        int u = (t >= off) ? part[t - off] : 0;
        __syncthreads();
        part[t] += u;
        __syncthreads();
    }
    int run = part[t] - s;   // exclusive prefix of this thread's chunk
    for (int i = begin; i < end; i++) {
        rowptr[i] = run; cursor[i] = run;
        run += deg[i];
    }
    if (t == SCAN_T - 1) rowptr[N_NODES] = part[SCAN_T - 1];
}

__global__ void csr_fill(const int* __restrict__ src, const int* __restrict__ dst,
                         int* __restrict__ cursor, int* __restrict__ csr_src) {
    int gid = blockIdx.x * blockDim.x + threadIdx.x;
    int stride = gridDim.x * blockDim.x;
    for (int e = gid; e < N_EDGES; e += stride) {
        int d = dst[e];
        int p = atomicAdd(&cursor[d], 1);
        csr_src[p] = src[e];
    }
}

// ---------------- dtype prep ----------------
// W[128][K] f32 -> Wb[128][KP] bf16 (zero-padded K..KP)
__global__ void wconv(const float* __restrict__ W, unsigned short* __restrict__ Wb, int K, int KP) {
    int idx = blockIdx.x * 256 + threadIdx.x;
    if (idx >= 128 * KP) return;
    int n = idx / KP, k = idx - n * KP;
    Wb[idx] = (k < K) ? f2bf(W[n * K + k]) : (unsigned short)0;
}

// x[100k][50] f32 -> xbf[100k][64] bf16 zero-padded
__global__ void xconv(const float* __restrict__ x, unsigned short* __restrict__ xbf) {
    int idx = blockIdx.x * 256 + threadIdx.x;
    if (idx >= N_NODES * 64) return;
    int n = idx >> 6, c = idx & 63;
    float v = (c < IN_F) ? x[(size_t)n * IN_F + c] : 0.f;
    xbf[idx] = f2bf(v);
}

// ---------------- pull aggregation (writes bf16) ----------------
// wave per node, F=50 f32 in -> bf16 [64] out (padded)
__global__ __launch_bounds__(256) void gather_f50(const float* __restrict__ x,
                                                  const int* __restrict__ rowptr,
                                                  const int* __restrict__ csr_src,
                                                  unsigned short* __restrict__ aggbf) {
    int gid = blockIdx.x * blockDim.x + threadIdx.x;
    int n = gid >> 6;
    int lane = threadIdx.x & 63;
    if (n >= N_NODES) return;
    int jb = rowptr[n], je = rowptr[n + 1];
    float acc = 0.f;
    int j = jb;
    for (; j + 1 < je; j += 2) {
        int s0 = csr_src[j], s1 = csr_src[j + 1];
        float v0 = 0.f, v1 = 0.f;
        if (lane < IN_F) { v0 = x[(size_t)s0 * IN_F + lane]; v1 = x[(size_t)s1 * IN_F + lane]; }
        acc += v0 + v1;
    }
    if (j < je) {
        int s0 = csr_src[j];
        if (lane < IN_F) acc += x[(size_t)s0 * IN_F + lane];
    }
    aggbf[(size_t)n * 64 + lane] = (lane < IN_F) ? f2bf(acc) : (unsigned short)0;
}

// wave per node, F=128 bf16 source: lane holds 2 features (one dword), bf16 out
__global__ __launch_bounds__(256) void gather_bf128(const unsigned short* __restrict__ h,
                                                    const int* __restrict__ rowptr,
                                                    const int* __restrict__ csr_src,
                                                    unsigned short* __restrict__ aggbf) {
    int gid = blockIdx.x * blockDim.x + threadIdx.x;
    int n = gid >> 6;
    int lane = threadIdx.x & 63;
    if (n >= N_NODES) return;
    int jb = rowptr[n], je = rowptr[n + 1];
    float acc0 = 0.f, acc1 = 0.f;
    const unsigned* hu = reinterpret_cast<const unsigned*>(h);
    int j = jb;
    for (; j + 1 < je; j += 2) {
        int s0 = csr_src[j], s1 = csr_src[j + 1];
        unsigned v0 = hu[(size_t)s0 * 64 + lane];
        unsigned v1 = hu[(size_t)s1 * 64 + lane];
        acc0 += bf2f((unsigned short)(v0 & 0xFFFF)) + bf2f((unsigned short)(v1 & 0xFFFF));
        acc1 += bf2f((unsigned short)(v0 >> 16)) + bf2f((unsigned short)(v1 >> 16));
    }
    if (j < je) {
        int s0 = csr_src[j];
        unsigned v0 = hu[(size_t)s0 * 64 + lane];
        acc0 += bf2f((unsigned short)(v0 & 0xFFFF));
        acc1 += bf2f((unsigned short)(v0 >> 16));
    }
    unsigned pk = (unsigned)f2bf(acc0) | ((unsigned)f2bf(acc1) << 16);
    reinterpret_cast<unsigned*>(aggbf)[(size_t)n * 64 + lane] = pk;
}

// ---------------- MFMA fused linear ----------------
// out = [relu](A1 @ B1^T + bias + A2 @ B2^T), A bf16 [M][K*], B bf16 [128][K*] (= W layout!)
// Block = 4 waves x 16 rows. Wave: 8 n-tiles of 16x16x32 MFMA, acc 8 x f32x4.
// Fragment layout (m89/m91-verified): A lane&15=row, k=(lane>>4)*8+j (16B contiguous);
// B lane&15=col(n), same k range; D col=lane&15, row=(lane>>4)*4+reg.
// In-place safe (hout may alias A2): each wave reads only its own 16 rows before writing them.
template <int K1, int K2, bool RELU, bool POOL>
__global__ __launch_bounds__(256) void mfma_linear(
    const unsigned short* __restrict__ A1, const unsigned short* __restrict__ A2,
    const unsigned short* __restrict__ B1, const unsigned short* __restrict__ B2,
    const float* __restrict__ bias, unsigned short* __restrict__ hout,
    const int* __restrict__ batch, float* __restrict__ pooled) {
    const int tid = threadIdx.x;
    const int wave = tid >> 6;
    const int lane = tid & 63;
    const int m0 = blockIdx.x * 64 + wave * 16;
    const int ar = lane & 15;   // A row within tile / B col within tile / D col
    const int kh = lane >> 4;   // k-half (8 elems)
    int arow = m0 + ar; if (arow > N_NODES - 1) arow = N_NODES - 1;

    f32x4 acc[8];
#pragma unroll
    for (int nt = 0; nt < 8; nt++) acc[nt] = (f32x4){0.f, 0.f, 0.f, 0.f};

#pragma unroll
    for (int ks = 0; ks < K1 / 32; ks++) {
        bf16x8 a = *reinterpret_cast<const bf16x8*>(A1 + (size_t)arow * K1 + ks * 32 + kh * 8);
#pragma unroll
        for (int nt = 0; nt < 8; nt++) {
            bf16x8 b = *reinterpret_cast<const bf16x8*>(B1 + (size_t)(nt * 16 + ar) * K1 + ks * 32 + kh * 8);
            acc[nt] = __builtin_amdgcn_mfma_f32_16x16x32_bf16(a, b, acc[nt], 0, 0, 0);
        }
    }
#pragma unroll
    for (int ks = 0; ks < K2 / 32; ks++) {
        bf16x8 a = *reinterpret_cast<const bf16x8*>(A2 + (size_t)arow * K2 + ks * 32 + kh * 8);
#pragma unroll
        for (int nt = 0; nt < 8; nt++) {
            bf16x8 b = *reinterpret_cast<const bf16x8*>(B2 + (size_t)(nt * 16 + ar) * K2 + ks * 32 + kh * 8);
            acc[nt] = __builtin_amdgcn_mfma_f32_16x16x32_bf16(a, b, acc[nt], 0, 0, 0);
        }
    }

    float bv[8];
#pragma unroll
    for (int nt = 0; nt < 8; nt++) bv[nt] = bias[nt * 16 + ar];

#pragma unroll
    for (int r = 0; r < 4; r++) {
        int row = m0 + kh * 4 + r;
        if (row >= N_NODES) continue;
        if (RELU) {
#pragma unroll
            for (int nt = 0; nt < 8; nt++) {
                float v = fmaxf(acc[nt][r] + bv[nt], 0.f);
                hout[(size_t)row * HID + nt * 16 + ar] = f2bf(v);
            }
        }
        if (POOL) {
            int g = batch[row];
#pragma unroll
            for (int nt = 0; nt < 8; nt++) {
                atomicAdd(&pooled[(size_t)g * HID + nt * 16 + ar], acc[nt][r] + bv[nt]);
            }
        }
    }
}

__global__ void final_linear(const float* __restrict__ pooled, const float* __restrict__ counts,
                             const float* __restrict__ W_lin, const float* __restrict__ b_lin,
                             float* __restrict__ out) {
    __shared__ float p[HID];
    int g = blockIdx.x, tid = threadIdx.x;
    float c = fmaxf(counts[g], 1.f);
    p[tid] = pooled[(size_t)g * HID + tid] / c;
    __syncthreads();
    if (tid < 4) {
        float s = b_lin[tid];
#pragma unroll 8
        for (int k = 0; k < HID; k++) s += p[k] * W_lin[tid * HID + k];
        out[g * 4 + tid] = s;
    }
}

extern "C" void kernel_launch(void* const* d_in, const int* in_sizes, int n_in,
                              void* d_out, int out_size, void* d_ws, size_t ws_size,
                              hipStream_t stream) {
    (void)in_sizes; (void)n_in; (void)out_size; (void)ws_size;
    const float* x      = (const float*)d_in[0];
    const int*   ei     = (const int*)d_in[1];
    const int*   batch  = (const int*)d_in[2];
    const float* W_rel1 = (const float*)d_in[3];
    const float* b_rel1 = (const float*)d_in[4];
    const float* W_root1= (const float*)d_in[5];
    const float* W_rel2 = (const float*)d_in[6];
    const float* b_rel2 = (const float*)d_in[7];
    const float* W_root2= (const float*)d_in[8];
    const float* W_rel3 = (const float*)d_in[9];
    const float* b_rel3 = (const float*)d_in[10];
    const float* W_root3= (const float*)d_in[11];
    const float* W_lin  = (const float*)d_in[12];
    const float* b_lin  = (const float*)d_in[13];
    const int* src = ei;
    const int* dst = ei + N_EDGES;

    char* ws = (char*)d_ws;
    size_t off = 0;
    auto alloc = [&](size_t bytes) { void* p = ws + off; off += (bytes + 255) & ~(size_t)255; return p; };
    unsigned short* aggbf    = (unsigned short*)alloc((size_t)N_NODES * HID * 2); // 25.6 MB (layer1 uses [.][64] slice)
    unsigned short* h1       = (unsigned short*)alloc((size_t)N_NODES * HID * 2); // 25.6 MB (layers 2,3 in-place)
    unsigned short* xbf      = (unsigned short*)alloc((size_t)N_NODES * 64 * 2);  // 12.8 MB
    int*            deg      = (int*)alloc((size_t)N_NODES * 4);
    int*            rowptr   = (int*)alloc((size_t)(N_NODES + 1) * 4);
    int*            cursor   = (int*)alloc((size_t)N_NODES * 4);
    int*            csr_src  = (int*)alloc((size_t)N_EDGES * 4);                  // 6.4 MB
    unsigned short* Wb_rel1  = (unsigned short*)alloc(128 * 64 * 2);
    unsigned short* Wb_root1 = (unsigned short*)alloc(128 * 64 * 2);
    unsigned short* Wb_rel2  = (unsigned short*)alloc(128 * 128 * 2);
    unsigned short* Wb_root2 = (unsigned short*)alloc(128 * 128 * 2);
    unsigned short* Wb_rel3  = (unsigned short*)alloc(128 * 128 * 2);
    unsigned short* Wb_root3 = (unsigned short*)alloc(128 * 128 * 2);
    float*          pooled   = (float*)alloc((size_t)N_GRAPHS * HID * 4);
    float*          counts   = (float*)alloc(N_GRAPHS * 4);

    // ---- CSR build
    hipMemsetAsync(deg, 0, (size_t)N_NODES * 4, stream);
    deg_hist<<<2048, 256, 0, stream>>>(dst, deg);
    scan_deg<<<1, SCAN_T, 0, stream>>>(deg, rowptr, cursor);
    csr_fill<<<2048, 256, 0, stream>>>(src, dst, cursor, csr_src);

    // ---- dtype prep
    wconv<<<32, 256, 0, stream>>>(W_rel1, Wb_rel1, IN_F, 64);
    wconv<<<32, 256, 0, stream>>>(W_root1, Wb_root1, IN_F, 64);
    wconv<<<64, 256, 0, stream>>>(W_rel2, Wb_rel2, HID, HID);
    wconv<<<64, 256, 0, stream>>>(W_root2, Wb_root2, HID, HID);
    wconv<<<64, 256, 0, stream>>>(W_rel3, Wb_rel3, HID, HID);
    wconv<<<64, 256, 0, stream>>>(W_root3, Wb_root3, HID, HID);
    xconv<<<(N_NODES * 64 + 255) / 256, 256, 0, stream>>>(x, xbf);
    hipMemsetAsync(pooled, 0, (size_t)N_GRAPHS * HID * 4, stream);
    count_nodes<<<2, 256, 0, stream>>>(batch, counts);

    const int GATHER_BLOCKS = (N_NODES * 64 + 255) / 256;  // wave per node
    const int MFMA_BLOCKS = (N_NODES + 63) / 64;

    // ---- layer 1: pull-aggregate x (F=50), MFMA linears + relu -> h1 (bf16)
    gather_f50<<<GATHER_BLOCKS, 256, 0, stream>>>(x, rowptr, csr_src, aggbf);
    mfma_linear<64, 64, true, false><<<MFMA_BLOCKS, 256, 0, stream>>>(
        aggbf, xbf, Wb_rel1, Wb_root1, b_rel1, h1, nullptr, nullptr);

    // ---- layer 2: pull-aggregate h1 (F=128 bf16), MFMA linears + relu -> h1 (in-place)
    gather_bf128<<<GATHER_BLOCKS, 256, 0, stream>>>(h1, rowptr, csr_src, aggbf);
    mfma_linear<128, 128, true, false><<<MFMA_BLOCKS, 256, 0, stream>>>(
        aggbf, h1, Wb_rel2, Wb_root2, b_rel2, h1, nullptr, nullptr);

    // ---- layer 3: pull-aggregate h1, MFMA linears (no relu) + fused mean-pool
    gather_bf128<<<GATHER_BLOCKS, 256, 0, stream>>>(h1, rowptr, csr_src, aggbf);
    mfma_linear<128, 128, false, true><<<MFMA_BLOCKS, 256, 0, stream>>>(
        aggbf, h1, Wb_rel3, Wb_root3, b_rel3, nullptr, batch, pooled);

    final_linear<<<N_GRAPHS, HID, 0, stream>>>(pooled, counts, W_lin, b_lin, (float*)d_out);
}

// Round 4
// 913.766 us; speedup vs baseline: 13.8751x; 1.2470x over previous
//
#include <hip/hip_runtime.h>
#include <hip/hip_bf16.h>
#include <stdint.h>

#define N_NODES 100000
#define N_EDGES 1600000
#define N_GRAPHS 512
#define IN_F 50
#define HID 128

typedef __attribute__((ext_vector_type(8))) short bf16x8;
typedef __attribute__((ext_vector_type(4))) float f32x4;

__device__ __forceinline__ float bf2f(unsigned short s) {
    return __uint_as_float(((unsigned)s) << 16);
}
__device__ __forceinline__ unsigned short f2bf(float f) {
    unsigned u = __float_as_uint(f);
    u = (u + 0x7FFFu + ((u >> 16) & 1u)) >> 16;   // round-to-nearest-even
    return (unsigned short)u;
}

// counts[g] = #nodes in graph g (batch is sorted) -- atomic-free binary search
__global__ void count_nodes(const int* __restrict__ batch, float* __restrict__ counts) {
    int g = blockIdx.x * blockDim.x + threadIdx.x;
    if (g >= N_GRAPHS) return;
    int lo = 0, hi = N_NODES;
    while (lo < hi) { int m = (lo + hi) >> 1; if (batch[m] < g) lo = m + 1; else hi = m; }
    int lo2 = lo, hi2 = N_NODES;
    while (lo2 < hi2) { int m = (lo2 + hi2) >> 1; if (batch[m] < g + 1) lo2 = m + 1; else hi2 = m; }
    counts[g] = (float)(lo2 - lo);
}

// ---------------- CSR build ----------------
__global__ void deg_hist(const int* __restrict__ dst, int* __restrict__ deg) {
    int gid = blockIdx.x * blockDim.x + threadIdx.x;
    int stride = gridDim.x * blockDim.x;
    for (int e = gid; e < N_EDGES; e += stride) atomicAdd(&deg[dst[e]], 1);
}

// -------- 3-phase grid-wide exclusive scan of deg[100000] --------
#define SCAN_BLOCKS ((N_NODES + 1023) / 1024)   // 98

__global__ __launch_bounds__(256) void scan_phase1(const int* __restrict__ deg,
                                                   int* __restrict__ blocksum) {
    __shared__ int red[256];
    int b = blockIdx.x, t = threadIdx.x;
    int base = b * 1024 + t * 4;
    int s = 0;
#pragma unroll
    for (int i = 0; i < 4; i++) { int idx = base + i; if (idx < N_NODES) s += deg[idx]; }
    red[t] = s;
    __syncthreads();
    for (int off = 128; off > 0; off >>= 1) {
        if (t < off) red[t] += red[t + off];
        __syncthreads();
    }
    if (t == 0) blocksum[b] = red[0];
}

__global__ __launch_bounds__(128) void scan_phase2(const int* __restrict__ blocksum,
                                                   int* __restrict__ blockoff) {
    __shared__ int v[SCAN_BLOCKS];
    int t = threadIdx.x;
    if (t < SCAN_BLOCKS) v[t] = blocksum[t];
    __syncthreads();
    if (t == 0) {
        int run = 0;
        for (int i = 0; i < SCAN_BLOCKS; i++) { blockoff[i] = run; run += v[i]; }
        blockoff[SCAN_BLOCKS] = run;
    }
}

__global__ __launch_bounds__(256) void scan_phase3(const int* __restrict__ deg,
                                                   const int* __restrict__ blockoff,
                                                   int* __restrict__ rowptr,
                                                   int* __restrict__ cursor) {
    __shared__ int red[256];
    int b = blockIdx.x, t = threadIdx.x;
    int base = b * 1024 + t * 4;
    int e[4];
    int s = 0;
#pragma unroll
    for (int i = 0; i < 4; i++) {
        int idx = base + i;
        e[i] = (idx < N_NODES) ? deg[idx] : 0;
        s += e[i];
    }
    red[t] = s;
    __syncthreads();
    for (int off = 1; off < 256; off <<= 1) {
        int u = (t >= off) ? red[t - off] : 0;
        __syncthreads();
        red[t] += u;
        __syncthreads();
    }
    int prefix = red[t] - s + blockoff[b];   // exclusive prefix of this thread's 4 elems
#pragma unroll
    for (int i = 0; i < 4; i++) {
        int idx = base + i;
        if (idx < N_NODES) { rowptr[idx] = prefix; cursor[idx] = prefix; prefix += e[i]; }
    }
    if (b == 0 && t == 0) rowptr[N_NODES] = blockoff[SCAN_BLOCKS];
}

__global__ void csr_fill(const int* __restrict__ src, const int* __restrict__ dst,
                         int* __restrict__ cursor, int* __restrict__ csr_src) {
    int gid = blockIdx.x * blockDim.x + threadIdx.x;
    int stride = gridDim.x * blockDim.x;
    for (int e = gid; e < N_EDGES; e += stride) {
        int d = dst[e];
        int p = atomicAdd(&cursor[d], 1);
        csr_src[p] = src[e];
    }
}

// ---------------- dtype prep ----------------
// all six weight matrices f32 -> bf16 in one launch (layer1 pair zero-padded 50->64)
__global__ __launch_bounds__(256) void wconv_all(
    const float* __restrict__ Wr1, const float* __restrict__ Wo1,
    const float* __restrict__ Wr2, const float* __restrict__ Wo2,
    const float* __restrict__ Wr3, const float* __restrict__ Wo3,
    unsigned short* __restrict__ o_r1, unsigned short* __restrict__ o_o1,
    unsigned short* __restrict__ o_r2, unsigned short* __restrict__ o_o2,
    unsigned short* __restrict__ o_r3, unsigned short* __restrict__ o_o3) {
    int idx = blockIdx.x * 256 + threadIdx.x;
    if (idx < 128 * 64) {
        int n = idx >> 6, k = idx & 63;
        unsigned short a = 0, b = 0;
        if (k < IN_F) { a = f2bf(Wr1[n * IN_F + k]); b = f2bf(Wo1[n * IN_F + k]); }
        o_r1[idx] = a; o_o1[idx] = b;
        return;
    }
    idx -= 128 * 64;
    if (idx < 128 * 128) {
        o_r2[idx] = f2bf(Wr2[idx]); o_o2[idx] = f2bf(Wo2[idx]);
        o_r3[idx] = f2bf(Wr3[idx]); o_o3[idx] = f2bf(Wo3[idx]);
    }
}

// x[100k][50] f32 -> xbf[100k][64] bf16 zero-padded
__global__ void xconv(const float* __restrict__ x, unsigned short* __restrict__ xbf) {
    int idx = blockIdx.x * 256 + threadIdx.x;
    if (idx >= N_NODES * 64) return;
    int n = idx >> 6, c = idx & 63;
    float v = (c < IN_F) ? x[(size_t)n * IN_F + c] : 0.f;
    xbf[idx] = f2bf(v);
}

// ---------------- pull aggregation (writes bf16) ----------------
// wave per node, F=50 f32 in -> bf16 [64] out (padded)
__global__ __launch_bounds__(256) void gather_f50(const float* __restrict__ x,
                                                  const int* __restrict__ rowptr,
                                                  const int* __restrict__ csr_src,
                                                  unsigned short* __restrict__ aggbf) {
    int gid = blockIdx.x * blockDim.x + threadIdx.x;
    int n = gid >> 6;
    int lane = threadIdx.x & 63;
    if (n >= N_NODES) return;
    int jb = rowptr[n], je = rowptr[n + 1];
    float acc = 0.f;
    int j = jb;
    for (; j + 1 < je; j += 2) {
        int s0 = csr_src[j], s1 = csr_src[j + 1];
        float v0 = 0.f, v1 = 0.f;
        if (lane < IN_F) { v0 = x[(size_t)s0 * IN_F + lane]; v1 = x[(size_t)s1 * IN_F + lane]; }
        acc += v0 + v1;
    }
    if (j < je) {
        int s0 = csr_src[j];
        if (lane < IN_F) acc += x[(size_t)s0 * IN_F + lane];
    }
    aggbf[(size_t)n * 64 + lane] = (lane < IN_F) ? f2bf(acc) : (unsigned short)0;
}

// wave per node, F=128 bf16 source: lane holds 2 features (one dword), bf16 out
__global__ __launch_bounds__(256) void gather_bf128(const unsigned short* __restrict__ h,
                                                    const int* __restrict__ rowptr,
                                                    const int* __restrict__ csr_src,
                                                    unsigned short* __restrict__ aggbf) {
    int gid = blockIdx.x * blockDim.x + threadIdx.x;
    int n = gid >> 6;
    int lane = threadIdx.x & 63;
    if (n >= N_NODES) return;
    int jb = rowptr[n], je = rowptr[n + 1];
    float acc0 = 0.f, acc1 = 0.f;
    const unsigned* hu = reinterpret_cast<const unsigned*>(h);
    int j = jb;
    for (; j + 1 < je; j += 2) {
        int s0 = csr_src[j], s1 = csr_src[j + 1];
        unsigned v0 = hu[(size_t)s0 * 64 + lane];
        unsigned v1 = hu[(size_t)s1 * 64 + lane];
        acc0 += bf2f((unsigned short)(v0 & 0xFFFF)) + bf2f((unsigned short)(v1 & 0xFFFF));
        acc1 += bf2f((unsigned short)(v0 >> 16)) + bf2f((unsigned short)(v1 >> 16));
    }
    if (j < je) {
        int s0 = csr_src[j];
        unsigned v0 = hu[(size_t)s0 * 64 + lane];
        acc0 += bf2f((unsigned short)(v0 & 0xFFFF));
        acc1 += bf2f((unsigned short)(v0 >> 16));
    }
    unsigned pk = (unsigned)f2bf(acc0) | ((unsigned)f2bf(acc1) << 16);
    reinterpret_cast<unsigned*>(aggbf)[(size_t)n * 64 + lane] = pk;
}

// ---------------- MFMA fused linear ----------------
// out = [relu](A1 @ B1^T + bias + A2 @ B2^T), A bf16 [M][K*], B bf16 [128][K*] (= W layout!)
// Block = 4 waves x 16 rows. Wave: 8 n-tiles of 16x16x32 MFMA, acc 8 x f32x4.
// Fragment layout (m89/m91-verified): A lane&15=row, k=(lane>>4)*8+j (16B contiguous);
// B lane&15=col(n), same k range; D col=lane&15, row=(lane>>4)*4+reg.
// In-place safe (hout may alias A2): each wave reads only its own 16 rows before writing them.
template <int K1, int K2, bool RELU, bool POOL>
__global__ __launch_bounds__(256) void mfma_linear(
    const unsigned short* __restrict__ A1, const unsigned short* __restrict__ A2,
    const unsigned short* __restrict__ B1, const unsigned short* __restrict__ B2,
    const float* __restrict__ bias, unsigned short* __restrict__ hout,
    const int* __restrict__ batch, float* __restrict__ pooled) {
    const int tid = threadIdx.x;
    const int wave = tid >> 6;
    const int lane = tid & 63;
    const int m0 = blockIdx.x * 64 + wave * 16;
    const int ar = lane & 15;   // A row within tile / B col within tile / D col
    const int kh = lane >> 4;   // k-half (8 elems)
    int arow = m0 + ar; if (arow > N_NODES - 1) arow = N_NODES - 1;

    f32x4 acc[8];
#pragma unroll
    for (int nt = 0; nt < 8; nt++) acc[nt] = (f32x4){0.f, 0.f, 0.f, 0.f};

#pragma unroll
    for (int ks = 0; ks < K1 / 32; ks++) {
        bf16x8 a = *reinterpret_cast<const bf16x8*>(A1 + (size_t)arow * K1 + ks * 32 + kh * 8);
#pragma unroll
        for (int nt = 0; nt < 8; nt++) {
            bf16x8 b = *reinterpret_cast<const bf16x8*>(B1 + (size_t)(nt * 16 + ar) * K1 + ks * 32 + kh * 8);
            acc[nt] = __builtin_amdgcn_mfma_f32_16x16x32_bf16(a, b, acc[nt], 0, 0, 0);
        }
    }
#pragma unroll
    for (int ks = 0; ks < K2 / 32; ks++) {
        bf16x8 a = *reinterpret_cast<const bf16x8*>(A2 + (size_t)arow * K2 + ks * 32 + kh * 8);
#pragma unroll
        for (int nt = 0; nt < 8; nt++) {
            bf16x8 b = *reinterpret_cast<const bf16x8*>(B2 + (size_t)(nt * 16 + ar) * K2 + ks * 32 + kh * 8);
            acc[nt] = __builtin_amdgcn_mfma_f32_16x16x32_bf16(a, b, acc[nt], 0, 0, 0);
        }
    }

    float bv[8];
#pragma unroll
    for (int nt = 0; nt < 8; nt++) bv[nt] = bias[nt * 16 + ar];

#pragma unroll
    for (int r = 0; r < 4; r++) {
        int row = m0 + kh * 4 + r;
        if (row >= N_NODES) continue;
        if (RELU) {
#pragma unroll
            for (int nt = 0; nt < 8; nt++) {
                float v = fmaxf(acc[nt][r] + bv[nt], 0.f);
                hout[(size_t)row * HID + nt * 16 + ar] = f2bf(v);
            }
        }
        if (POOL) {
            int g = batch[row];
#pragma unroll
            for (int nt = 0; nt < 8; nt++) {
                atomicAdd(&pooled[(size_t)g * HID + nt * 16 + ar], acc[nt][r] + bv[nt]);
            }
        }
    }
}

__global__ void final_linear(const float* __restrict__ pooled, const float* __restrict__ counts,
                             const float* __restrict__ W_lin, const float* __restrict__ b_lin,
                             float* __restrict__ out) {
    __shared__ float p[HID];
    int g = blockIdx.x, tid = threadIdx.x;
    float c = fmaxf(counts[g], 1.f);
    p[tid] = pooled[(size_t)g * HID + tid] / c;
    __syncthreads();
    if (tid < 4) {
        float s = b_lin[tid];
#pragma unroll 8
        for (int k = 0; k < HID; k++) s += p[k] * W_lin[tid * HID + k];
        out[g * 4 + tid] = s;
    }
}

extern "C" void kernel_launch(void* const* d_in, const int* in_sizes, int n_in,
                              void* d_out, int out_size, void* d_ws, size_t ws_size,
                              hipStream_t stream) {
    (void)in_sizes; (void)n_in; (void)out_size; (void)ws_size;
    const float* x      = (const float*)d_in[0];
    const int*   ei     = (const int*)d_in[1];
    const int*   batch  = (const int*)d_in[2];
    const float* W_rel1 = (const float*)d_in[3];
    const float* b_rel1 = (const float*)d_in[4];
    const float* W_root1= (const float*)d_in[5];
    const float* W_rel2 = (const float*)d_in[6];
    const float* b_rel2 = (const float*)d_in[7];
    const float* W_root2= (const float*)d_in[8];
    const float* W_rel3 = (const float*)d_in[9];
    const float* b_rel3 = (const float*)d_in[10];
    const float* W_root3= (const float*)d_in[11];
    const float* W_lin  = (const float*)d_in[12];
    const float* b_lin  = (const float*)d_in[13];
    const int* src = ei;
    const int* dst = ei + N_EDGES;

    char* ws = (char*)d_ws;
    size_t off = 0;
    auto alloc = [&](size_t bytes) { void* p = ws + off; off += (bytes + 255) & ~(size_t)255; return p; };
    unsigned short* aggbf    = (unsigned short*)alloc((size_t)N_NODES * HID * 2); // 25.6 MB (layer1 uses [.][64] slice)
    unsigned short* h1       = (unsigned short*)alloc((size_t)N_NODES * HID * 2); // 25.6 MB (layers 2,3 in-place)
    unsigned short* xbf      = (unsigned short*)alloc((size_t)N_NODES * 64 * 2);  // 12.8 MB
    int*            deg      = (int*)alloc((size_t)N_NODES * 4);
    int*            rowptr   = (int*)alloc((size_t)(N_NODES + 1) * 4);
    int*            cursor   = (int*)alloc((size_t)N_NODES * 4);
    int*            csr_src  = (int*)alloc((size_t)N_EDGES * 4);                  // 6.4 MB
    int*            blocksum = (int*)alloc((size_t)(SCAN_BLOCKS + 1) * 4);
    int*            blockoff = (int*)alloc((size_t)(SCAN_BLOCKS + 1) * 4);
    unsigned short* Wb_rel1  = (unsigned short*)alloc(128 * 64 * 2);
    unsigned short* Wb_root1 = (unsigned short*)alloc(128 * 64 * 2);
    unsigned short* Wb_rel2  = (unsigned short*)alloc(128 * 128 * 2);
    unsigned short* Wb_root2 = (unsigned short*)alloc(128 * 128 * 2);
    unsigned short* Wb_rel3  = (unsigned short*)alloc(128 * 128 * 2);
    unsigned short* Wb_root3 = (unsigned short*)alloc(128 * 128 * 2);
    float*          pooled   = (float*)alloc((size_t)N_GRAPHS * HID * 4);
    float*          counts   = (float*)alloc(N_GRAPHS * 4);

    // ---- CSR build (parallel scan)
    hipMemsetAsync(deg, 0, (size_t)N_NODES * 4, stream);
    deg_hist<<<2048, 256, 0, stream>>>(dst, deg);
    scan_phase1<<<SCAN_BLOCKS, 256, 0, stream>>>(deg, blocksum);
    scan_phase2<<<1, 128, 0, stream>>>(blocksum, blockoff);
    scan_phase3<<<SCAN_BLOCKS, 256, 0, stream>>>(deg, blockoff, rowptr, cursor);
    csr_fill<<<2048, 256, 0, stream>>>(src, dst, cursor, csr_src);

    // ---- dtype prep
    wconv_all<<<(128 * 64 + 128 * 128 + 255) / 256, 256, 0, stream>>>(
        W_rel1, W_root1, W_rel2, W_root2, W_rel3, W_root3,
        Wb_rel1, Wb_root1, Wb_rel2, Wb_root2, Wb_rel3, Wb_root3);
    xconv<<<(N_NODES * 64 + 255) / 256, 256, 0, stream>>>(x, xbf);
    hipMemsetAsync(pooled, 0, (size_t)N_GRAPHS * HID * 4, stream);
    count_nodes<<<2, 256, 0, stream>>>(batch, counts);

    const int GATHER_BLOCKS = (N_NODES * 64 + 255) / 256;  // wave per node
    const int MFMA_BLOCKS = (N_NODES + 63) / 64;

    // ---- layer 1: pull-aggregate x (F=50), MFMA linears + relu -> h1 (bf16)
    gather_f50<<<GATHER_BLOCKS, 256, 0, stream>>>(x, rowptr, csr_src, aggbf);
    mfma_linear<64, 64, true, false><<<MFMA_BLOCKS, 256, 0, stream>>>(
        aggbf, xbf, Wb_rel1, Wb_root1, b_rel1, h1, nullptr, nullptr);

    // ---- layer 2: pull-aggregate h1 (F=128 bf16), MFMA linears + relu -> h1 (in-place)
    gather_bf128<<<GATHER_BLOCKS, 256, 0, stream>>>(h1, rowptr, csr_src, aggbf);
    mfma_linear<128, 128, true, false><<<MFMA_BLOCKS, 256, 0, stream>>>(
        aggbf, h1, Wb_rel2, Wb_root2, b_rel2, h1, nullptr, nullptr);

    // ---- layer 3: pull-aggregate h1, MFMA linears (no relu) + fused mean-pool
    gather_bf128<<<GATHER_BLOCKS, 256, 0, stream>>>(h1, rowptr, csr_src, aggbf);
    mfma_linear<128, 128, false, true><<<MFMA_BLOCKS, 256, 0, stream>>>(
        aggbf, h1, Wb_rel3, Wb_root3, b_rel3, nullptr, batch, pooled);

    final_linear<<<N_GRAPHS, HID, 0, stream>>>(pooled, counts, W_lin, b_lin, (float*)d_out);
}